// Round 4
// baseline (375.160 us; speedup 1.0000x reference)
//
#include <hip/hip_runtime.h>
#include <hip/hip_bf16.h>

typedef unsigned short ushort;
typedef unsigned int uint;
typedef unsigned long long u64;

#define NN 4096
#define PP 128
#define QQ 128
#define HD 256
#define KH 8
#define DD 64
#define KK 16384  // P*Q

typedef short bf16x8 __attribute__((ext_vector_type(8)));
typedef float f32x4 __attribute__((ext_vector_type(4)));

__device__ inline void async_lds16(const void* g, void* l) {
  __builtin_amdgcn_global_load_lds(
      (const __attribute__((address_space(1))) unsigned int*)g,
      (__attribute__((address_space(3))) unsigned int*)l, 16, 0, 0);
}

__device__ inline uint bf16_rne_hibits(float z) {  // returns (bf16 bits)<<16
  uint u = __float_as_uint(z);
  return (u + 0x7FFFu + ((u >> 16) & 1u)) & 0xFFFF0000u;
}

// ---------------------------------------------------------------------------
// K0: split W fp32 -> bf16 hi + bf16 lo (residual), RNE both
// ---------------------------------------------------------------------------
__global__ __launch_bounds__(256) void k0_split(
    const float* __restrict__ W, ushort* __restrict__ hi, ushort* __restrict__ lo) {
  const int i = (blockIdx.x * 256 + threadIdx.x) * 4;
  const float4 w = *(const float4*)&W[i];
  ushort h4[4], l4[4];
  const float wf[4] = {w.x, w.y, w.z, w.w};
#pragma unroll
  for (int j = 0; j < 4; ++j) {
    uint hb = bf16_rne_hibits(wf[j]);
    h4[j] = hb >> 16;
    float r = wf[j] - __uint_as_float(hb);
    l4[j] = bf16_rne_hibits(r) >> 16;
  }
  *(ushort4*)&hi[i] = *(ushort4*)h4;
  *(ushort4*)&lo[i] = *(ushort4*)l4;
}

__global__ __launch_bounds__(256) void k_zero4(float* __restrict__ p) {
  const int i = (blockIdx.x * 256 + threadIdx.x) * 4;
  *(float4*)&p[i] = make_float4(0.f, 0.f, 0.f, 0.f);
}

// ---------------------------------------------------------------------------
// K1: bilinear via split-bf16 MFMA.  C[4096,256] = Z @ Wsplit^T, Z on the fly.
// Block 128n x 256h (4 waves of 64n x 128h), BK=32, K-split 8 -> atomicAdd.
// z-split: truncation (exact residual) + v_perm hi16 packing (~4 VALU/elem).
// ---------------------------------------------------------------------------
__global__ __launch_bounds__(256, 2) void k1_bilinear(
    const float* __restrict__ xp, const float* __restrict__ xn,
    const ushort* __restrict__ Whi, const ushort* __restrict__ Wlo,
    float* __restrict__ xout) {
  __shared__ ushort whi[256 * 32];   // [h][k], XOR-swizzled 16B segs
  __shared__ ushort wlo[256 * 32];
  __shared__ ushort zhi[128 * 40];   // [n][k] padded 32->40
  __shared__ ushort zlo[128 * 40];
  __shared__ float xpt[16][128];     // [p][n]

  const int t = threadIdx.x;
  const int n0 = blockIdx.x * 128;
  const int kb = blockIdx.y * (KK / 8);   // 2048-wide K chunk
  const int pb = kb >> 7;                 // 16 p values per block

  for (int idx = t; idx < 2048; idx += 256) {
    const int p = idx & 15, n = idx >> 4;
    xpt[p][n] = xp[(size_t)(n0 + n) * PP + pb + p];
  }

  const int l = t & 63, w = t >> 6;
  const int wr = (w >> 1) * 64, wc = (w & 1) * 128;

  int aoff[4], boff[8];
#pragma unroll
  for (int i = 0; i < 4; ++i)
    aoff[i] = (wr + i * 16 + (l & 15)) * 40 + (l >> 4) * 8;
#pragma unroll
  for (int j = 0; j < 8; ++j) {
    const int hr = wc + j * 16 + (l & 15);
    boff[j] = hr * 32 + (((l >> 4) ^ ((hr ^ (hr >> 2)) & 3)) * 8);
  }

  // W staging: 4 row-groups of 64, 16B segs XOR-swizzled on global side
  const int shb = t >> 2, seg = t & 3;
  int gsw[4];
#pragma unroll
  for (int g = 0; g < 4; ++g) {
    const int r = shb + 64 * g;
    gsw[g] = seg ^ ((r ^ (r >> 2)) & 3);
  }

  const int zn = t >> 1, zko = (t & 1) * 16;

  f32x4 acc[4][8];
#pragma unroll
  for (int i = 0; i < 4; ++i)
#pragma unroll
    for (int j = 0; j < 8; ++j) acc[i][j] = (f32x4)0.f;

  for (int c = 0; c < 64; ++c) {
    const int kc = kb + c * 32;
    const int pl = c >> 2;
    const int q0 = (c & 3) * 32;

    __syncthreads();  // previous step's fragment reads done

#pragma unroll
    for (int g = 0; g < 4; ++g) {
      const int r = shb + 64 * g;
      async_lds16(Whi + (size_t)r * KK + kc + gsw[g] * 8, whi + r * 32 + seg * 8);
      async_lds16(Wlo + (size_t)r * KK + kc + gsw[g] * 8, wlo + r * 32 + seg * 8);
    }

    // form Z tile: 16 elems/thread, trunc split + perm pack
    {
      const float xpv = xpt[pl][zn];
      const float* xr = xn + (size_t)(n0 + zn) * QQ + q0 + zko;
      float4 v0 = ((const float4*)xr)[0];
      float4 v1 = ((const float4*)xr)[1];
      float4 v2 = ((const float4*)xr)[2];
      float4 v3 = ((const float4*)xr)[3];
      float zz[16] = {v0.x, v0.y, v0.z, v0.w, v1.x, v1.y, v1.z, v1.w,
                      v2.x, v2.y, v2.z, v2.w, v3.x, v3.y, v3.z, v3.w};
      union { uint u[8]; uint4 q[2]; } ph, pq;
#pragma unroll
      for (int j = 0; j < 8; ++j) {
        const float z0 = xpv * zz[2 * j], z1 = xpv * zz[2 * j + 1];
        const uint u0 = __float_as_uint(z0), u1 = __float_as_uint(z1);
        const float h0f = __uint_as_float(u0 & 0xFFFF0000u);
        const float h1f = __uint_as_float(u1 & 0xFFFF0000u);
        const uint r0 = __float_as_uint(z0 - h0f);
        const uint r1 = __float_as_uint(z1 - h1f);
        ph.u[j] = __builtin_amdgcn_perm(u1, u0, 0x07060302);
        pq.u[j] = __builtin_amdgcn_perm(r1, r0, 0x07060302);
      }
      const int zo = zn * 40 + zko;
      *(uint4*)&zhi[zo] = ph.q[0];
      *(uint4*)&zhi[zo + 8] = ph.q[1];
      *(uint4*)&zlo[zo] = pq.q[0];
      *(uint4*)&zlo[zo + 8] = pq.q[1];
    }

    __syncthreads();  // W (vmcnt drained) + Z visible

    bf16x8 Ah[4], Al[4];
#pragma unroll
    for (int i = 0; i < 4; ++i) {
      Ah[i] = *(const bf16x8*)&zhi[aoff[i]];
      Al[i] = *(const bf16x8*)&zlo[aoff[i]];
    }
#pragma unroll
    for (int j = 0; j < 8; ++j) {
      const bf16x8 Bh = *(const bf16x8*)&whi[boff[j]];
      const bf16x8 Bl = *(const bf16x8*)&wlo[boff[j]];
#pragma unroll
      for (int i = 0; i < 4; ++i) {
        acc[i][j] = __builtin_amdgcn_mfma_f32_16x16x32_bf16(Ah[i], Bh, acc[i][j], 0, 0, 0);
        acc[i][j] = __builtin_amdgcn_mfma_f32_16x16x32_bf16(Ah[i], Bl, acc[i][j], 0, 0, 0);
        acc[i][j] = __builtin_amdgcn_mfma_f32_16x16x32_bf16(Al[i], Bh, acc[i][j], 0, 0, 0);
      }
    }
  }

#pragma unroll
  for (int i = 0; i < 4; ++i)
#pragma unroll
    for (int j = 0; j < 8; ++j) {
      const int row = n0 + wr + i * 16 + (l >> 4) * 4;
      const int col = wc + j * 16 + (l & 15);
#pragma unroll
      for (int r = 0; r < 4; ++r)
        atomicAdd(&xout[(size_t)(row + r) * HD + col], acc[i][j][r]);
    }
}

// ---------------------------------------------------------------------------
// K23: xt[k][n][d] = sum_h (x[n][h]+b[h]) * Wt[k][d][h]; fused u/v dots.
// ---------------------------------------------------------------------------
__global__ __launch_bounds__(256) void k23_xt(
    const float* __restrict__ x, const float* __restrict__ bb,
    const float* __restrict__ Wt, const float* __restrict__ av,
    float* __restrict__ xt, float* __restrict__ ssrc, float* __restrict__ sdst) {
  __shared__ float x_t[64][68];
  __shared__ float wt_t[64][68];
  __shared__ float red1[64][17];
  __shared__ float red2[64][17];
  const int t = threadIdx.x;
  const int n0 = blockIdx.x * 64;
  const int k = blockIdx.y;
  const int nb = 4 * (t & 15), db = 4 * (t >> 4);
  float acc[4][4] = {{0.f, 0.f, 0.f, 0.f}, {0.f, 0.f, 0.f, 0.f},
                     {0.f, 0.f, 0.f, 0.f}, {0.f, 0.f, 0.f, 0.f}};
  for (int h0 = 0; h0 < HD; h0 += 64) {
    __syncthreads();
    for (int idx = t; idx < 4096; idx += 256) {
      int hl = idx & 63, r = idx >> 6;
      x_t[hl][r] = x[(n0 + r) * HD + h0 + hl] + bb[h0 + hl];
      wt_t[hl][r] = Wt[k * (DD * HD) + r * HD + h0 + hl];
    }
    __syncthreads();
#pragma unroll 8
    for (int h = 0; h < 64; ++h) {
      const float4 xv = *(const float4*)&x_t[h][nb];
      const float4 wv = *(const float4*)&wt_t[h][db];
      acc[0][0] += xv.x * wv.x; acc[0][1] += xv.x * wv.y;
      acc[0][2] += xv.x * wv.z; acc[0][3] += xv.x * wv.w;
      acc[1][0] += xv.y * wv.x; acc[1][1] += xv.y * wv.y;
      acc[1][2] += xv.y * wv.z; acc[1][3] += xv.y * wv.w;
      acc[2][0] += xv.z * wv.x; acc[2][1] += xv.z * wv.y;
      acc[2][2] += xv.z * wv.z; acc[2][3] += xv.z * wv.w;
      acc[3][0] += xv.w * wv.x; acc[3][1] += xv.w * wv.y;
      acc[3][2] += xv.w * wv.z; acc[3][3] += xv.w * wv.w;
    }
  }
  const float4 a1 = *(const float4*)&av[k * (2 * DD) + db];
  const float4 a2 = *(const float4*)&av[k * (2 * DD) + DD + db];
#pragma unroll
  for (int i = 0; i < 4; ++i) {
    float4 o;
    o.x = acc[i][0]; o.y = acc[i][1]; o.z = acc[i][2]; o.w = acc[i][3];
    *(float4*)&xt[(k * NN + n0 + nb + i) * DD + db] = o;
    red1[nb + i][t >> 4] = acc[i][0] * a1.x + acc[i][1] * a1.y +
                           acc[i][2] * a1.z + acc[i][3] * a1.w;
    red2[nb + i][t >> 4] = acc[i][0] * a2.x + acc[i][1] * a2.y +
                           acc[i][2] * a2.z + acc[i][3] * a2.w;
  }
  __syncthreads();
  if (t < 64) {
    float s = 0.f;
#pragma unroll
    for (int g = 0; g < 16; ++g) s += red1[t][g];
    ssrc[k * NN + n0 + t] = s;
  } else if (t < 128) {
    const int r = t - 64;
    float s = 0.f;
#pragma unroll
    for (int g = 0; g < 16; ++g) s += red2[r][g];
    sdst[k * NN + n0 + r] = s;
  }
}

// ---------------------------------------------------------------------------
// K4a: per-head bitonic sort of v (ascending), packed u64 keys (branchless)
// ---------------------------------------------------------------------------
__global__ __launch_bounds__(1024) void k4_sort(
    const float* __restrict__ sdst, float* __restrict__ vsorted,
    int* __restrict__ perm) {
  __shared__ u64 kv[4096];
  const int k = blockIdx.x, t = threadIdx.x;
  for (int i = t; i < 4096; i += 1024) {
    const uint u = __float_as_uint(sdst[k * NN + i]);
    const uint key = (u & 0x80000000u) ? ~u : (u | 0x80000000u);
    kv[i] = ((u64)key << 32) | (uint)i;
  }
  __syncthreads();
  for (int len = 2; len <= 4096; len <<= 1) {
    for (int s = len >> 1; s > 0; s >>= 1) {
      for (int i = t; i < 4096; i += 1024) {
        const int j = i ^ s;
        if (j > i) {
          const bool asc = ((i & len) == 0);
          const u64 a = kv[i], b = kv[j];
          const bool sw = (a > b) == asc;
          kv[i] = sw ? b : a;
          kv[j] = sw ? a : b;
        }
      }
      __syncthreads();
    }
  }
  for (int i = t; i < 4096; i += 1024) {
    const u64 e = kv[i];
    const uint key = (uint)(e >> 32);
    const uint u = (key & 0x80000000u) ? (key ^ 0x80000000u) : ~key;
    vsorted[k * NN + i] = __uint_as_float(u);
    perm[k * NN + i] = (int)(e & 0xFFFFFFFFu);
  }
}

// ---------------------------------------------------------------------------
// K4b: per-(head,chunk) sums of e^v·xt (hi) and e^{0.2v}·xt (lo); slot 64 = weight
// ---------------------------------------------------------------------------
__global__ __launch_bounds__(128) void k4b_chunksum(
    const float* __restrict__ vs, const int* __restrict__ perm,
    const float* __restrict__ xt, float* __restrict__ Chi, float* __restrict__ Clo) {
  const int c = blockIdx.x, k = blockIdx.y, t = threadIdx.x;
  if (t >= 65) return;
  const int base = k * NN + c * 64;
  float shi = 0.f, slo = 0.f;
  for (int i = 0; i < 64; ++i) {
    const float v = vs[base + i];
    const int p = perm[base + i];
    const float val = (t < 64) ? xt[((size_t)(k * NN + p)) * DD + t] : 1.0f;
    shi += __expf(v) * val;
    slo += __expf(0.2f * v) * val;
  }
  Chi[(k * 64 + c) * 65 + t] = shi;
  Clo[(k * 64 + c) * 65 + t] = slo;
}

// ---------------------------------------------------------------------------
// K4c: scan chunk sums: CloS = exclusive prefix (fwd), ChiS = inclusive suffix
// ---------------------------------------------------------------------------
__global__ __launch_bounds__(128) void k4c_scan(
    const float* __restrict__ Chi, const float* __restrict__ Clo,
    float* __restrict__ ChiS, float* __restrict__ CloS) {
  const int k = blockIdx.x, t = threadIdx.x;
  if (t >= 65) return;
  float run = 0.f;
  for (int c = 0; c < 64; ++c) {
    const float tmp = Clo[(k * 64 + c) * 65 + t];
    CloS[(k * 64 + c) * 65 + t] = run;
    run += tmp;
  }
  run = 0.f;
  for (int c = 63; c >= 0; --c) {
    run += Chi[(k * 64 + c) * 65 + t];
    ChiS[(k * 64 + c) * 65 + t] = run;
  }
}

// ---------------------------------------------------------------------------
// K4d: expand to per-position arrays.
// Plo[pos] = sum_{i<pos} e^{0.2 v_i} xt_i   (exclusive prefix)
// Phi[pos] = sum_{i>=pos} e^{v_i} xt_i      (inclusive suffix, no subtraction)
// ---------------------------------------------------------------------------
__global__ __launch_bounds__(128) void k4d_expand(
    const float* __restrict__ vs, const int* __restrict__ perm,
    const float* __restrict__ xt, const float* __restrict__ ChiS,
    const float* __restrict__ CloS, float* __restrict__ Phi,
    float* __restrict__ Plo) {
  const int c = blockIdx.x, k = blockIdx.y, t = threadIdx.x;
  if (t >= 65) return;
  const int base = k * NN + c * 64;
  float run = CloS[(k * 64 + c) * 65 + t];
  for (int i = 0; i < 64; ++i) {
    const int pos = c * 64 + i;
    const float v = vs[base + i];
    const int p = perm[base + i];
    const float val = (t < 64) ? xt[((size_t)(k * NN + p)) * DD + t] : 1.0f;
    Plo[((size_t)(k * 4097) + pos) * 65 + t] = run;
    run += __expf(0.2f * v) * val;
  }
  if (c == 63) Plo[((size_t)(k * 4097) + 4096) * 65 + t] = run;
  run = (c < 63) ? ChiS[(k * 64 + c + 1) * 65 + t] : 0.f;
  for (int i = 63; i >= 0; --i) {
    const int pos = c * 64 + i;
    const float v = vs[base + i];
    const int p = perm[base + i];
    const float val = (t < 64) ? xt[((size_t)(k * NN + p)) * DD + t] : 1.0f;
    run += __expf(v) * val;
    Phi[((size_t)(k * 4097) + pos) * 65 + t] = run;
  }
  if (c == 63) Phi[((size_t)(k * 4097) + 4096) * 65 + t] = 0.f;
}

// ---------------------------------------------------------------------------
// K6: per query: binary search threshold, combine, tanh, store.
// ---------------------------------------------------------------------------
__global__ __launch_bounds__(256) void k6_final(
    const float* __restrict__ ssrc, const float* __restrict__ vsorted,
    const float* __restrict__ Phi, const float* __restrict__ Plo,
    float* __restrict__ out) {
  const int t = threadIdx.x;
  const int qi = blockIdx.x * 4 + (t >> 6);  // = k*4096 + n
  const int d = t & 63;
  const int k = qi >> 12, n = qi & 4095;
  const float u = ssrc[qi];
  const float thr = -u;
  const float* vs = vsorted + k * NN;
  int lo = 0, hi = 4096;
  while (lo < hi) {
    const int mid = (lo + hi) >> 1;
    if (vs[mid] < thr) lo = mid + 1; else hi = mid;
  }
  const size_t rb = ((size_t)(k * 4097) + lo) * 65;
  const float eu = __expf(u), el = __expf(0.2f * u);
  const float num = eu * Phi[rb + d] + el * Plo[rb + d];
  const float den = eu * Phi[rb + 64] + el * Plo[rb + 64];
  out[(size_t)n * (KH * DD) + k * DD + d] = tanhf(num / den);
}

extern "C" void kernel_launch(void* const* d_in, const int* in_sizes, int n_in,
                              void* d_out, int out_size, void* d_ws, size_t ws_size,
                              hipStream_t stream) {
  const float* xp = (const float*)d_in[0];
  const float* xn = (const float*)d_in[1];
  const float* W = (const float*)d_in[2];
  const float* bb = (const float*)d_in[3];
  const float* Wt = (const float*)d_in[4];
  const float* av = (const float*)d_in[5];
  float* out = (float*)d_out;

  char* ws = (char*)d_ws;
  ushort* Whi  = (ushort*)(ws);                     // 8 MB
  ushort* Wlo  = (ushort*)(ws + 8388608);           // 8 MB
  float* x     = (float*)(ws + 16777216);           // 4 MB
  float* xt    = (float*)(ws + 20971520);           // 8 MB
  float* ssrc  = (float*)(ws + 29360128);           // 128 KB
  float* sdst  = (float*)(ws + 29491200);           // 128 KB
  float* vsort = (float*)(ws + 29622272);           // 128 KB
  int*   perm  = (int*)  (ws + 29753344);           // 128 KB
  float* Chi   = (float*)(ws + 29884416);           // 130 KB
  float* Clo   = (float*)(ws + 30017536);           // 130 KB
  float* ChiS  = (float*)(ws + 30150656);           // 130 KB
  float* CloS  = (float*)(ws + 30283776);           // 130 KB
  float* Phi   = (float*)(ws + 30416896);           // 8.33 MB
  float* Plo   = (float*)(ws + 38938656);           // 8.33 MB  (end ~45.3 MB)

  k0_split<<<(HD * PP * QQ) / 1024, 256, 0, stream>>>(W, Whi, Wlo);
  k_zero4<<<(NN * HD) / 1024, 256, 0, stream>>>(x);
  k1_bilinear<<<dim3(NN / 128, 8), 256, 0, stream>>>(xp, xn, Whi, Wlo, x);
  k23_xt<<<dim3(NN / 64, KH), 256, 0, stream>>>(x, bb, Wt, av, xt, ssrc, sdst);
  k4_sort<<<KH, 1024, 0, stream>>>(sdst, vsort, perm);
  k4b_chunksum<<<dim3(64, KH), 128, 0, stream>>>(vsort, perm, xt, Chi, Clo);
  k4c_scan<<<KH, 128, 0, stream>>>(Chi, Clo, ChiS, CloS);
  k4d_expand<<<dim3(64, KH), 128, 0, stream>>>(vsort, perm, xt, ChiS, CloS, Phi, Plo);
  k6_final<<<(KH * NN) / 4, 256, 0, stream>>>(ssrc, vsort, Phi, Plo, out);
}

// Round 5
// 353.008 us; speedup vs baseline: 1.0628x; 1.0628x over previous
//
#include <hip/hip_runtime.h>
#include <hip/hip_bf16.h>

typedef unsigned short ushort;
typedef unsigned int uint;
typedef unsigned long long u64;

#define NN 4096
#define PP 128
#define QQ 128
#define HD 256
#define KH 8
#define DD 64
#define KK 16384  // P*Q

typedef short bf16x8 __attribute__((ext_vector_type(8)));
typedef float f32x4 __attribute__((ext_vector_type(4)));

__device__ inline void async_lds16(const void* g, void* l) {
  __builtin_amdgcn_global_load_lds(
      (const __attribute__((address_space(1))) unsigned int*)g,
      (__attribute__((address_space(3))) unsigned int*)l, 16, 0, 0);
}

__device__ inline uint bf16_rne_hibits(float z) {  // returns (bf16 bits)<<16
  uint u = __float_as_uint(z);
  return (u + 0x7FFFu + ((u >> 16) & 1u)) & 0xFFFF0000u;
}

// ---------------------------------------------------------------------------
// K0: split W fp32 -> bf16 hi + bf16 lo (residual), RNE both
// ---------------------------------------------------------------------------
__global__ __launch_bounds__(256) void k0_split(
    const float* __restrict__ W, ushort* __restrict__ hi, ushort* __restrict__ lo) {
  const int i = (blockIdx.x * 256 + threadIdx.x) * 4;
  const float4 w = *(const float4*)&W[i];
  ushort h4[4], l4[4];
  const float wf[4] = {w.x, w.y, w.z, w.w};
#pragma unroll
  for (int j = 0; j < 4; ++j) {
    uint hb = bf16_rne_hibits(wf[j]);
    h4[j] = hb >> 16;
    float r = wf[j] - __uint_as_float(hb);
    l4[j] = bf16_rne_hibits(r) >> 16;
  }
  *(ushort4*)&hi[i] = *(ushort4*)h4;
  *(ushort4*)&lo[i] = *(ushort4*)l4;
}

__global__ __launch_bounds__(256) void k_zero4(float* __restrict__ p) {
  const int i = (blockIdx.x * 256 + threadIdx.x) * 4;
  *(float4*)&p[i] = make_float4(0.f, 0.f, 0.f, 0.f);
}

// ---------------------------------------------------------------------------
// K1: bilinear via split-bf16 MFMA.  C[4096,256] = Z @ Wsplit^T, Z on the fly.
// Block 128n x 256h (4 waves of 64n x 128h), BK=32, K-split 16 -> atomicAdd.
// grid (32,16)=512 blocks @ 2 blocks/CU -> full 256-CU coverage.
// z-split: truncation (exact residual) + v_perm hi16 packing (~4 VALU/elem).
// ---------------------------------------------------------------------------
__global__ __launch_bounds__(256, 2) void k1_bilinear(
    const float* __restrict__ xp, const float* __restrict__ xn,
    const ushort* __restrict__ Whi, const ushort* __restrict__ Wlo,
    float* __restrict__ xout) {
  __shared__ ushort whi[256 * 32];   // [h][k], XOR-swizzled 16B segs
  __shared__ ushort wlo[256 * 32];
  __shared__ ushort zhi[128 * 40];   // [n][k] padded 32->40
  __shared__ ushort zlo[128 * 40];
  __shared__ float xpt[8][128];      // [p][n]

  const int t = threadIdx.x;
  const int n0 = blockIdx.x * 128;
  const int kb = blockIdx.y * (KK / 16);  // 1024-wide K chunk
  const int pb = kb >> 7;                 // 8 p values per block

  for (int idx = t; idx < 1024; idx += 256) {
    const int p = idx & 7, n = idx >> 3;
    xpt[p][n] = xp[(size_t)(n0 + n) * PP + pb + p];
  }

  const int l = t & 63, w = t >> 6;
  const int wr = (w >> 1) * 64, wc = (w & 1) * 128;

  int aoff[4], boff[8];
#pragma unroll
  for (int i = 0; i < 4; ++i)
    aoff[i] = (wr + i * 16 + (l & 15)) * 40 + (l >> 4) * 8;
#pragma unroll
  for (int j = 0; j < 8; ++j) {
    const int hr = wc + j * 16 + (l & 15);
    boff[j] = hr * 32 + (((l >> 4) ^ ((hr ^ (hr >> 2)) & 3)) * 8);
  }

  // W staging: 4 row-groups of 64, 16B segs XOR-swizzled on global side
  const int shb = t >> 2, seg = t & 3;
  int gsw[4];
#pragma unroll
  for (int g = 0; g < 4; ++g) {
    const int r = shb + 64 * g;
    gsw[g] = seg ^ ((r ^ (r >> 2)) & 3);
  }

  const int zn = t >> 1, zko = (t & 1) * 16;

  f32x4 acc[4][8];
#pragma unroll
  for (int i = 0; i < 4; ++i)
#pragma unroll
    for (int j = 0; j < 8; ++j) acc[i][j] = (f32x4)0.f;

  for (int c = 0; c < 32; ++c) {
    const int kc = kb + c * 32;
    const int pl = c >> 2;             // local p index (0..7)
    const int q0 = (c & 3) * 32;       // q base within row

    __syncthreads();  // previous step's fragment reads done

#pragma unroll
    for (int g = 0; g < 4; ++g) {
      const int r = shb + 64 * g;
      async_lds16(Whi + (size_t)r * KK + kc + gsw[g] * 8, whi + r * 32 + seg * 8);
      async_lds16(Wlo + (size_t)r * KK + kc + gsw[g] * 8, wlo + r * 32 + seg * 8);
    }

    // form Z tile: 16 elems/thread, trunc split + perm pack
    {
      const float xpv = xpt[pl][zn];
      const float* xr = xn + (size_t)(n0 + zn) * QQ + q0 + zko;
      float4 v0 = ((const float4*)xr)[0];
      float4 v1 = ((const float4*)xr)[1];
      float4 v2 = ((const float4*)xr)[2];
      float4 v3 = ((const float4*)xr)[3];
      float zz[16] = {v0.x, v0.y, v0.z, v0.w, v1.x, v1.y, v1.z, v1.w,
                      v2.x, v2.y, v2.z, v2.w, v3.x, v3.y, v3.z, v3.w};
      union { uint u[8]; uint4 q[2]; } ph, pq;
#pragma unroll
      for (int j = 0; j < 8; ++j) {
        const float z0 = xpv * zz[2 * j], z1 = xpv * zz[2 * j + 1];
        const uint u0 = __float_as_uint(z0), u1 = __float_as_uint(z1);
        const float h0f = __uint_as_float(u0 & 0xFFFF0000u);
        const float h1f = __uint_as_float(u1 & 0xFFFF0000u);
        const uint r0 = __float_as_uint(z0 - h0f);
        const uint r1 = __float_as_uint(z1 - h1f);
        ph.u[j] = __builtin_amdgcn_perm(u1, u0, 0x07060302);
        pq.u[j] = __builtin_amdgcn_perm(r1, r0, 0x07060302);
      }
      const int zo = zn * 40 + zko;
      *(uint4*)&zhi[zo] = ph.q[0];
      *(uint4*)&zhi[zo + 8] = ph.q[1];
      *(uint4*)&zlo[zo] = pq.q[0];
      *(uint4*)&zlo[zo + 8] = pq.q[1];
    }

    __syncthreads();  // W (vmcnt drained) + Z visible

    bf16x8 Ah[4], Al[4];
#pragma unroll
    for (int i = 0; i < 4; ++i) {
      Ah[i] = *(const bf16x8*)&zhi[aoff[i]];
      Al[i] = *(const bf16x8*)&zlo[aoff[i]];
    }
#pragma unroll
    for (int j = 0; j < 8; ++j) {
      const bf16x8 Bh = *(const bf16x8*)&whi[boff[j]];
      const bf16x8 Bl = *(const bf16x8*)&wlo[boff[j]];
#pragma unroll
      for (int i = 0; i < 4; ++i) {
        acc[i][j] = __builtin_amdgcn_mfma_f32_16x16x32_bf16(Ah[i], Bh, acc[i][j], 0, 0, 0);
        acc[i][j] = __builtin_amdgcn_mfma_f32_16x16x32_bf16(Ah[i], Bl, acc[i][j], 0, 0, 0);
        acc[i][j] = __builtin_amdgcn_mfma_f32_16x16x32_bf16(Al[i], Bh, acc[i][j], 0, 0, 0);
      }
    }
  }

#pragma unroll
  for (int i = 0; i < 4; ++i)
#pragma unroll
    for (int j = 0; j < 8; ++j) {
      const int row = n0 + wr + i * 16 + (l >> 4) * 4;
      const int col = wc + j * 16 + (l & 15);
#pragma unroll
      for (int r = 0; r < 4; ++r)
        atomicAdd(&xout[(size_t)(row + r) * HD + col], acc[i][j][r]);
    }
}

// ---------------------------------------------------------------------------
// K23: xt[k][n][d] = sum_h (x[n][h]+b[h]) * Wt[k][d][h]; fused u/v dots.
// ---------------------------------------------------------------------------
__global__ __launch_bounds__(256) void k23_xt(
    const float* __restrict__ x, const float* __restrict__ bb,
    const float* __restrict__ Wt, const float* __restrict__ av,
    float* __restrict__ xt, float* __restrict__ ssrc, float* __restrict__ sdst) {
  __shared__ float x_t[64][68];
  __shared__ float wt_t[64][68];
  __shared__ float red1[64][17];
  __shared__ float red2[64][17];
  const int t = threadIdx.x;
  const int n0 = blockIdx.x * 64;
  const int k = blockIdx.y;
  const int nb = 4 * (t & 15), db = 4 * (t >> 4);
  float acc[4][4] = {{0.f, 0.f, 0.f, 0.f}, {0.f, 0.f, 0.f, 0.f},
                     {0.f, 0.f, 0.f, 0.f}, {0.f, 0.f, 0.f, 0.f}};
  for (int h0 = 0; h0 < HD; h0 += 64) {
    __syncthreads();
    for (int idx = t; idx < 4096; idx += 256) {
      int hl = idx & 63, r = idx >> 6;
      x_t[hl][r] = x[(n0 + r) * HD + h0 + hl] + bb[h0 + hl];
      wt_t[hl][r] = Wt[k * (DD * HD) + r * HD + h0 + hl];
    }
    __syncthreads();
#pragma unroll 8
    for (int h = 0; h < 64; ++h) {
      const float4 xv = *(const float4*)&x_t[h][nb];
      const float4 wv = *(const float4*)&wt_t[h][db];
      acc[0][0] += xv.x * wv.x; acc[0][1] += xv.x * wv.y;
      acc[0][2] += xv.x * wv.z; acc[0][3] += xv.x * wv.w;
      acc[1][0] += xv.y * wv.x; acc[1][1] += xv.y * wv.y;
      acc[1][2] += xv.y * wv.z; acc[1][3] += xv.y * wv.w;
      acc[2][0] += xv.z * wv.x; acc[2][1] += xv.z * wv.y;
      acc[2][2] += xv.z * wv.z; acc[2][3] += xv.z * wv.w;
      acc[3][0] += xv.w * wv.x; acc[3][1] += xv.w * wv.y;
      acc[3][2] += xv.w * wv.z; acc[3][3] += xv.w * wv.w;
    }
  }
  const float4 a1 = *(const float4*)&av[k * (2 * DD) + db];
  const float4 a2 = *(const float4*)&av[k * (2 * DD) + DD + db];
#pragma unroll
  for (int i = 0; i < 4; ++i) {
    float4 o;
    o.x = acc[i][0]; o.y = acc[i][1]; o.z = acc[i][2]; o.w = acc[i][3];
    *(float4*)&xt[(k * NN + n0 + nb + i) * DD + db] = o;
    red1[nb + i][t >> 4] = acc[i][0] * a1.x + acc[i][1] * a1.y +
                           acc[i][2] * a1.z + acc[i][3] * a1.w;
    red2[nb + i][t >> 4] = acc[i][0] * a2.x + acc[i][1] * a2.y +
                           acc[i][2] * a2.z + acc[i][3] * a2.w;
  }
  __syncthreads();
  if (t < 64) {
    float s = 0.f;
#pragma unroll
    for (int g = 0; g < 16; ++g) s += red1[t][g];
    ssrc[k * NN + n0 + t] = s;
  } else if (t < 128) {
    const int r = t - 64;
    float s = 0.f;
#pragma unroll
    for (int g = 0; g < 16; ++g) s += red2[r][g];
    sdst[k * NN + n0 + r] = s;
  }
}

// ---------------------------------------------------------------------------
// K4a: rank-and-scatter sort replacement. rank_m = #{kv' < kv_m} over packed
// u64 keys (monotone float map in high 32, index in low 32 -> exact total
// order, branchless, LDS broadcast reads). grid (16, KH) x 256.
// ---------------------------------------------------------------------------
__global__ __launch_bounds__(256) void k4_rank(
    const float* __restrict__ sdst, float* __restrict__ vsorted,
    int* __restrict__ perm) {
  __shared__ u64 kv[4096];
  const int k = blockIdx.y, t = threadIdx.x;
  for (int i = t; i < 4096; i += 256) {
    const uint u = __float_as_uint(sdst[k * NN + i]);
    const uint key = (u & 0x80000000u) ? ~u : (u | 0x80000000u);
    kv[i] = ((u64)key << 32) | (uint)i;
  }
  __syncthreads();
  const int m = blockIdx.x * 256 + t;
  const u64 my = kv[m];
  int cnt = 0;
#pragma unroll 8
  for (int j = 0; j < 4096; ++j) cnt += (kv[j] < my) ? 1 : 0;
  const uint key = (uint)(my >> 32);
  const uint u = (key & 0x80000000u) ? (key ^ 0x80000000u) : ~key;
  vsorted[k * NN + cnt] = __uint_as_float(u);
  perm[k * NN + cnt] = (int)(my & 0xFFFFFFFFu);
}

// ---------------------------------------------------------------------------
// K4b: per-(head,chunk) sums of e^v·xt (hi) and e^{0.2v}·xt (lo); slot 64 =
// weight (computed redundantly per-lane, lane 0 writes).
// ---------------------------------------------------------------------------
__global__ __launch_bounds__(64) void k4b_chunksum(
    const float* __restrict__ vs, const int* __restrict__ perm,
    const float* __restrict__ xt, float* __restrict__ Chi, float* __restrict__ Clo) {
  const int c = blockIdx.x, k = blockIdx.y, t = threadIdx.x;
  const int base = k * NN + c * 64;
  float shi = 0.f, slo = 0.f, whs = 0.f, wls = 0.f;
  for (int i = 0; i < 64; ++i) {
    const float v = vs[base + i];
    const int p = perm[base + i];
    const float val = xt[((size_t)(k * NN + p)) * DD + t];
    const float eh = __expf(v), el = __expf(0.2f * v);
    shi += eh * val; slo += el * val;
    whs += eh; wls += el;
  }
  const int cb = (k * 64 + c) * 65;
  Chi[cb + t] = shi;
  Clo[cb + t] = slo;
  if (t == 0) { Chi[cb + 64] = whs; Clo[cb + 64] = wls; }
}

// ---------------------------------------------------------------------------
// K4c: scan chunk sums: CloS = exclusive prefix (fwd), ChiS = inclusive suffix
// ---------------------------------------------------------------------------
__global__ __launch_bounds__(128) void k4c_scan(
    const float* __restrict__ Chi, const float* __restrict__ Clo,
    float* __restrict__ ChiS, float* __restrict__ CloS) {
  const int k = blockIdx.x, t = threadIdx.x;
  if (t >= 65) return;
  float run = 0.f;
  for (int c = 0; c < 64; ++c) {
    const float tmp = Clo[(k * 64 + c) * 65 + t];
    CloS[(k * 64 + c) * 65 + t] = run;
    run += tmp;
  }
  run = 0.f;
  for (int c = 63; c >= 0; --c) {
    run += Chi[(k * 64 + c) * 65 + t];
    ChiS[(k * 64 + c) * 65 + t] = run;
  }
}

// ---------------------------------------------------------------------------
// K4d: expand to per-position arrays.
// Plo[pos] = sum_{i<pos} e^{0.2 v_i} xt_i   (exclusive prefix)
// Phi[pos] = sum_{i>=pos} e^{v_i} xt_i      (inclusive suffix, no subtraction)
// ---------------------------------------------------------------------------
__global__ __launch_bounds__(64) void k4d_expand(
    const float* __restrict__ vs, const int* __restrict__ perm,
    const float* __restrict__ xt, const float* __restrict__ ChiS,
    const float* __restrict__ CloS, float* __restrict__ Phi,
    float* __restrict__ Plo) {
  const int c = blockIdx.x, k = blockIdx.y, t = threadIdx.x;
  const int base = k * NN + c * 64;
  const int cb = (k * 64 + c) * 65;
  float run = CloS[cb + t];
  float wrun = CloS[cb + 64];
  for (int i = 0; i < 64; ++i) {
    const int pos = c * 64 + i;
    const float v = vs[base + i];
    const int p = perm[base + i];
    const float val = xt[((size_t)(k * NN + p)) * DD + t];
    const size_t rb = ((size_t)(k * 4097) + pos) * 65;
    Plo[rb + t] = run;
    if (t == 0) Plo[rb + 64] = wrun;
    const float el = __expf(0.2f * v);
    run += el * val;
    wrun += el;
  }
  if (c == 63) {
    const size_t rb = ((size_t)(k * 4097) + 4096) * 65;
    Plo[rb + t] = run;
    if (t == 0) Plo[rb + 64] = wrun;
  }
  run = (c < 63) ? ChiS[cb + 65 + t] : 0.f;
  wrun = (c < 63) ? ChiS[cb + 65 + 64] : 0.f;
  for (int i = 63; i >= 0; --i) {
    const int pos = c * 64 + i;
    const float v = vs[base + i];
    const int p = perm[base + i];
    const float val = xt[((size_t)(k * NN + p)) * DD + t];
    const float eh = __expf(v);
    run += eh * val;
    wrun += eh;
    const size_t rb = ((size_t)(k * 4097) + pos) * 65;
    Phi[rb + t] = run;
    if (t == 0) Phi[rb + 64] = wrun;
  }
  if (c == 63) {
    const size_t rb = ((size_t)(k * 4097) + 4096) * 65;
    Phi[rb + t] = 0.f;
    if (t == 0) Phi[rb + 64] = 0.f;
  }
}

// ---------------------------------------------------------------------------
// K6: per query: binary search threshold, combine, tanh, store.
// ---------------------------------------------------------------------------
__global__ __launch_bounds__(256) void k6_final(
    const float* __restrict__ ssrc, const float* __restrict__ vsorted,
    const float* __restrict__ Phi, const float* __restrict__ Plo,
    float* __restrict__ out) {
  const int t = threadIdx.x;
  const int qi = blockIdx.x * 4 + (t >> 6);  // = k*4096 + n
  const int d = t & 63;
  const int k = qi >> 12, n = qi & 4095;
  const float u = ssrc[qi];
  const float thr = -u;
  const float* vs = vsorted + k * NN;
  int lo = 0, hi = 4096;
  while (lo < hi) {
    const int mid = (lo + hi) >> 1;
    if (vs[mid] < thr) lo = mid + 1; else hi = mid;
  }
  const size_t rb = ((size_t)(k * 4097) + lo) * 65;
  const float eu = __expf(u), el = __expf(0.2f * u);
  const float num = eu * Phi[rb + d] + el * Plo[rb + d];
  const float den = eu * Phi[rb + 64] + el * Plo[rb + 64];
  out[(size_t)n * (KH * DD) + k * DD + d] = tanhf(num / den);
}

extern "C" void kernel_launch(void* const* d_in, const int* in_sizes, int n_in,
                              void* d_out, int out_size, void* d_ws, size_t ws_size,
                              hipStream_t stream) {
  const float* xp = (const float*)d_in[0];
  const float* xn = (const float*)d_in[1];
  const float* W = (const float*)d_in[2];
  const float* bb = (const float*)d_in[3];
  const float* Wt = (const float*)d_in[4];
  const float* av = (const float*)d_in[5];
  float* out = (float*)d_out;

  char* ws = (char*)d_ws;
  ushort* Whi  = (ushort*)(ws);                     // 8 MB
  ushort* Wlo  = (ushort*)(ws + 8388608);           // 8 MB
  float* x     = (float*)(ws + 16777216);           // 4 MB
  float* xt    = (float*)(ws + 20971520);           // 8 MB
  float* ssrc  = (float*)(ws + 29360128);           // 128 KB
  float* sdst  = (float*)(ws + 29491200);           // 128 KB
  float* vsort = (float*)(ws + 29622272);           // 128 KB
  int*   perm  = (int*)  (ws + 29753344);           // 128 KB
  float* Chi   = (float*)(ws + 29884416);           // 130 KB
  float* Clo   = (float*)(ws + 30017536);           // 130 KB
  float* ChiS  = (float*)(ws + 30150656);           // 130 KB
  float* CloS  = (float*)(ws + 30283776);           // 130 KB
  float* Phi   = (float*)(ws + 30416896);           // 8.33 MB
  float* Plo   = (float*)(ws + 38938656);           // 8.33 MB  (end ~45.3 MB)

  k0_split<<<(HD * PP * QQ) / 1024, 256, 0, stream>>>(W, Whi, Wlo);
  k_zero4<<<(NN * HD) / 1024, 256, 0, stream>>>(x);
  k1_bilinear<<<dim3(NN / 128, 16), 256, 0, stream>>>(xp, xn, Whi, Wlo, x);
  k23_xt<<<dim3(NN / 64, KH), 256, 0, stream>>>(x, bb, Wt, av, xt, ssrc, sdst);
  k4_rank<<<dim3(16, KH), 256, 0, stream>>>(sdst, vsort, perm);
  k4b_chunksum<<<dim3(64, KH), 64, 0, stream>>>(vsort, perm, xt, Chi, Clo);
  k4c_scan<<<KH, 128, 0, stream>>>(Chi, Clo, ChiS, CloS);
  k4d_expand<<<dim3(64, KH), 64, 0, stream>>>(vsort, perm, xt, ChiS, CloS, Phi, Plo);
  k6_final<<<(KH * NN) / 4, 256, 0, stream>>>(ssrc, vsort, Phi, Plo, out);
}

// Round 7
// 306.861 us; speedup vs baseline: 1.2226x; 1.1504x over previous
//
#include <hip/hip_runtime.h>
#include <hip/hip_bf16.h>

typedef unsigned short ushort;
typedef unsigned int uint;
typedef unsigned long long u64;
typedef _Float16 f16;

#define NN 4096
#define PP 128
#define QQ 128
#define HD 256
#define KH 8
#define DD 64
#define KK 16384  // P*Q

typedef _Float16 f16x2 __attribute__((ext_vector_type(2)));
typedef _Float16 f16x4 __attribute__((ext_vector_type(4)));
typedef _Float16 f16x8 __attribute__((ext_vector_type(8)));
typedef __fp16 fp16x2 __attribute__((ext_vector_type(2)));  // cvt_pkrtz return type
typedef float f32x4 __attribute__((ext_vector_type(4)));

__device__ inline void async_lds16(const void* g, void* l) {
  __builtin_amdgcn_global_load_lds(
      (const __attribute__((address_space(1))) unsigned int*)g,
      (__attribute__((address_space(3))) unsigned int*)l, 16, 0, 0);
}

// ---------------------------------------------------------------------------
// K0: split W fp32 -> f16 hi + f16 lo (exact residual; ~22-bit total)
// ---------------------------------------------------------------------------
__global__ __launch_bounds__(256) void k0_split(
    const float* __restrict__ W, f16* __restrict__ hi, f16* __restrict__ lo) {
  const int i = (blockIdx.x * 256 + threadIdx.x) * 4;
  const float4 w = *(const float4*)&W[i];
  const float wf[4] = {w.x, w.y, w.z, w.w};
  f16x4 hv, lv;
#pragma unroll
  for (int j = 0; j < 4; ++j) {
    const f16 h = (f16)wf[j];
    hv[j] = h;
    lv[j] = (f16)(wf[j] - (float)h);
  }
  *(f16x4*)&hi[i] = hv;
  *(f16x4*)&lo[i] = lv;
}

// K0b: same for Wt (8*64*256 = 131072 elems)
__global__ __launch_bounds__(256) void k0b_wtsplit(
    const float* __restrict__ Wt, f16* __restrict__ hi, f16* __restrict__ lo) {
  const int i = (blockIdx.x * 256 + threadIdx.x) * 4;
  const float4 w = *(const float4*)&Wt[i];
  const float wf[4] = {w.x, w.y, w.z, w.w};
  f16x4 hv, lv;
#pragma unroll
  for (int j = 0; j < 4; ++j) {
    const f16 h = (f16)wf[j];
    hv[j] = h;
    lv[j] = (f16)(wf[j] - (float)h);
  }
  *(f16x4*)&hi[i] = hv;
  *(f16x4*)&lo[i] = lv;
}

__global__ __launch_bounds__(256) void k_zero4(float* __restrict__ p) {
  const int i = (blockIdx.x * 256 + threadIdx.x) * 4;
  *(float4*)&p[i] = make_float4(0.f, 0.f, 0.f, 0.f);
}

// ---------------------------------------------------------------------------
// K1: bilinear via 2-pass fp16 MFMA. C[4096,256] = Z @ (Whi+Wlo)^T, Z rounded
// to fp16 on the fly. Block 128n x 256h, BK=32, K-split 16 -> atomicAdd.
// ---------------------------------------------------------------------------
__global__ __launch_bounds__(256, 2) void k1_bilinear(
    const float* __restrict__ xp, const float* __restrict__ xn,
    const f16* __restrict__ Whi, const f16* __restrict__ Wlo,
    float* __restrict__ xout) {
  __shared__ f16 whi[256 * 32];   // [h][k], XOR-swizzled 16B segs
  __shared__ f16 wlo[256 * 32];
  __shared__ f16 zhi[128 * 40];   // [n][k] padded 32->40
  __shared__ float xpt[8][128];   // [p][n]

  const int t = threadIdx.x;
  const int n0 = blockIdx.x * 128;
  const int kb = blockIdx.y * (KK / 16);  // 1024-wide K chunk
  const int pb = kb >> 7;                 // 8 p values per block

  for (int idx = t; idx < 1024; idx += 256) {
    const int p = idx & 7, n = idx >> 3;
    xpt[p][n] = xp[(size_t)(n0 + n) * PP + pb + p];
  }

  const int l = t & 63, w = t >> 6;
  const int wr = (w >> 1) * 64, wc = (w & 1) * 128;

  int aoff[4], boff[8];
#pragma unroll
  for (int i = 0; i < 4; ++i)
    aoff[i] = (wr + i * 16 + (l & 15)) * 40 + (l >> 4) * 8;
#pragma unroll
  for (int j = 0; j < 8; ++j) {
    const int hr = wc + j * 16 + (l & 15);
    boff[j] = hr * 32 + (((l >> 4) ^ ((hr ^ (hr >> 2)) & 3)) * 8);
  }

  const int shb = t >> 2, seg = t & 3;
  int gsw[4];
#pragma unroll
  for (int g = 0; g < 4; ++g) {
    const int r = shb + 64 * g;
    gsw[g] = seg ^ ((r ^ (r >> 2)) & 3);
  }

  const int zn = t >> 1, zko = (t & 1) * 16;

  f32x4 acc[4][8];
#pragma unroll
  for (int i = 0; i < 4; ++i)
#pragma unroll
    for (int j = 0; j < 8; ++j) acc[i][j] = (f32x4)0.f;

  for (int c = 0; c < 32; ++c) {
    const int kc = kb + c * 32;
    const int pl = c >> 2;             // local p index (0..7)
    const int q0 = (c & 3) * 32;       // q base within row

    __syncthreads();  // previous step's fragment reads done

#pragma unroll
    for (int g = 0; g < 4; ++g) {
      const int r = shb + 64 * g;
      async_lds16(Whi + (size_t)r * KK + kc + gsw[g] * 8, whi + r * 32 + seg * 8);
      async_lds16(Wlo + (size_t)r * KK + kc + gsw[g] * 8, wlo + r * 32 + seg * 8);
    }

    // form Z tile: 16 elems/thread, fp16 round via pkrtz (2 elems/op)
    {
      const float xpv = xpt[pl][zn];
      const float* xr = xn + (size_t)(n0 + zn) * QQ + q0 + zko;
      float4 v0 = ((const float4*)xr)[0];
      float4 v1 = ((const float4*)xr)[1];
      float4 v2 = ((const float4*)xr)[2];
      float4 v3 = ((const float4*)xr)[3];
      float zz[16] = {v0.x, v0.y, v0.z, v0.w, v1.x, v1.y, v1.z, v1.w,
                      v2.x, v2.y, v2.z, v2.w, v3.x, v3.y, v3.z, v3.w};
      union { uint u[8]; uint4 q[2]; } ph;
#pragma unroll
      for (int j = 0; j < 8; ++j) {
        union { fp16x2 h; uint u; } cv;
        cv.h = __builtin_amdgcn_cvt_pkrtz(xpv * zz[2 * j], xpv * zz[2 * j + 1]);
        ph.u[j] = cv.u;
      }
      const int zo = zn * 40 + zko;
      *(uint4*)&zhi[zo] = ph.q[0];
      *(uint4*)&zhi[zo + 8] = ph.q[1];
    }

    __syncthreads();  // W (vmcnt drained) + Z visible

    f16x8 Ah[4];
#pragma unroll
    for (int i = 0; i < 4; ++i) Ah[i] = *(const f16x8*)&zhi[aoff[i]];
#pragma unroll
    for (int j = 0; j < 8; ++j) {
      const f16x8 Bh = *(const f16x8*)&whi[boff[j]];
      const f16x8 Bl = *(const f16x8*)&wlo[boff[j]];
#pragma unroll
      for (int i = 0; i < 4; ++i) {
        acc[i][j] = __builtin_amdgcn_mfma_f32_16x16x32_f16(Ah[i], Bh, acc[i][j], 0, 0, 0);
        acc[i][j] = __builtin_amdgcn_mfma_f32_16x16x32_f16(Ah[i], Bl, acc[i][j], 0, 0, 0);
      }
    }
  }

#pragma unroll
  for (int i = 0; i < 4; ++i)
#pragma unroll
    for (int j = 0; j < 8; ++j) {
      const int row = n0 + wr + i * 16 + (l >> 4) * 4;
      const int col = wc + j * 16 + (l & 15);
#pragma unroll
      for (int r = 0; r < 4; ++r)
        atomicAdd(&xout[(size_t)(row + r) * HD + col], acc[i][j][r]);
    }
}

// ---------------------------------------------------------------------------
// K15: xh[n][h] = (f16)(x[n][h] + b[h])
// ---------------------------------------------------------------------------
__global__ __launch_bounds__(256) void k15_xcvt(
    const float* __restrict__ x, const float* __restrict__ bb,
    f16* __restrict__ xh) {
  const int i = (blockIdx.x * 256 + threadIdx.x) * 4;
  const int h = i & (HD - 1);
  const float4 xv = *(const float4*)&x[i];
  const float4 bv = *(const float4*)&bb[h];
  f16x4 o;
  o[0] = (f16)(xv.x + bv.x); o[1] = (f16)(xv.y + bv.y);
  o[2] = (f16)(xv.z + bv.z); o[3] = (f16)(xv.w + bv.w);
  *(f16x4*)&xh[i] = o;
}

// ---------------------------------------------------------------------------
// K23: xt[k][n][d] = sum_h xh[n][h] * (Wthi+Wtlo)[k*64+d][h]  (2-pass fp16 MFMA)
// Block 64n x 128cols, K=256 in BK=32 chunks. grid (64, 4).
// ---------------------------------------------------------------------------
__global__ __launch_bounds__(256) void k23_xt(
    const f16* __restrict__ xh, const f16* __restrict__ Wthi,
    const f16* __restrict__ Wtlo, float* __restrict__ xt) {
  __shared__ f16 ah[64 * 40];
  __shared__ f16 bh[128 * 32];
  __shared__ f16 bl[128 * 32];
  const int t = threadIdx.x;
  const int n0 = blockIdx.x * 64;
  const int c0 = blockIdx.y * 128;
  const int l = t & 63, w = t >> 6;
  const int wn = (w & 1) * 32, wcc = (w >> 1) * 64;

  int aoff[2], boff[4];
#pragma unroll
  for (int i = 0; i < 2; ++i)
    aoff[i] = (wn + i * 16 + (l & 15)) * 40 + (l >> 4) * 8;
#pragma unroll
  for (int j = 0; j < 4; ++j) {
    const int hr = wcc + j * 16 + (l & 15);
    boff[j] = hr * 32 + (((l >> 4) ^ ((hr ^ (hr >> 2)) & 3)) * 8);
  }

  f32x4 acc[2][4];
#pragma unroll
  for (int i = 0; i < 2; ++i)
#pragma unroll
    for (int j = 0; j < 4; ++j) acc[i][j] = (f32x4)0.f;

  for (int kc = 0; kc < HD; kc += 32) {
    __syncthreads();
    {  // A stage: 64 rows x 4 segs = 256 slots
      const int row = t >> 2, sg = t & 3;
      *(uint4*)&ah[row * 40 + sg * 8] =
          *(const uint4*)&xh[(size_t)(n0 + row) * HD + kc + sg * 8];
    }
#pragma unroll
    for (int g = 0; g < 2; ++g) {  // B stage: 128 cols x 4 segs = 512 slots
      const int slot = g * 256 + t;
      const int col = slot >> 2, ps = slot & 3;
      const int ls = ps ^ ((col ^ (col >> 2)) & 3);
      *(uint4*)&bh[col * 32 + ps * 8] =
          *(const uint4*)&Wthi[(size_t)(c0 + col) * HD + kc + ls * 8];
      *(uint4*)&bl[col * 32 + ps * 8] =
          *(const uint4*)&Wtlo[(size_t)(c0 + col) * HD + kc + ls * 8];
    }
    __syncthreads();
    f16x8 Af[2];
#pragma unroll
    for (int i = 0; i < 2; ++i) Af[i] = *(const f16x8*)&ah[aoff[i]];
#pragma unroll
    for (int j = 0; j < 4; ++j) {
      const f16x8 Bh = *(const f16x8*)&bh[boff[j]];
      const f16x8 Bl = *(const f16x8*)&bl[boff[j]];
#pragma unroll
      for (int i = 0; i < 2; ++i) {
        acc[i][j] = __builtin_amdgcn_mfma_f32_16x16x32_f16(Af[i], Bh, acc[i][j], 0, 0, 0);
        acc[i][j] = __builtin_amdgcn_mfma_f32_16x16x32_f16(Af[i], Bl, acc[i][j], 0, 0, 0);
      }
    }
  }
#pragma unroll
  for (int i = 0; i < 2; ++i)
#pragma unroll
    for (int j = 0; j < 4; ++j) {
      const int row = n0 + wn + i * 16 + (l >> 4) * 4;
      const int colg = c0 + wcc + j * 16 + (l & 15);
      const int k = colg >> 6, d = colg & 63;
#pragma unroll
      for (int r = 0; r < 4; ++r)
        xt[((size_t)(k * NN + row + r)) * DD + d] = acc[i][j][r];
    }
}

// ---------------------------------------------------------------------------
// K3: u = xt·a_src, v = xt·a_dst
// ---------------------------------------------------------------------------
__global__ __launch_bounds__(256) void k3_scores(
    const float* __restrict__ xt, const float* __restrict__ av,
    float* __restrict__ ssrc, float* __restrict__ sdst) {
  const int tid = blockIdx.x * 256 + threadIdx.x;
  const int k = tid >> 12;
  const float* xr = xt + (long)tid * DD;
  const float* a = av + k * (2 * DD);
  float s1 = 0.f, s2 = 0.f;
#pragma unroll
  for (int d = 0; d < DD; d += 4) {
    const float4 xv = *(const float4*)&xr[d];
    const float4 a1 = *(const float4*)&a[d];
    const float4 a2 = *(const float4*)&a[DD + d];
    s1 += xv.x * a1.x + xv.y * a1.y + xv.z * a1.z + xv.w * a1.w;
    s2 += xv.x * a2.x + xv.y * a2.y + xv.z * a2.z + xv.w * a2.w;
  }
  ssrc[tid] = s1;
  sdst[tid] = s2;
}

// ---------------------------------------------------------------------------
// K4a: rank-and-scatter "sort" (exact total order via packed u64 keys)
// ---------------------------------------------------------------------------
__global__ __launch_bounds__(256) void k4_rank(
    const float* __restrict__ sdst, float* __restrict__ vsorted,
    int* __restrict__ perm) {
  __shared__ u64 kv[4096];
  const int k = blockIdx.y, t = threadIdx.x;
  for (int i = t; i < 4096; i += 256) {
    const uint u = __float_as_uint(sdst[k * NN + i]);
    const uint key = (u & 0x80000000u) ? ~u : (u | 0x80000000u);
    kv[i] = ((u64)key << 32) | (uint)i;
  }
  __syncthreads();
  const int m = blockIdx.x * 256 + t;
  const u64 my = kv[m];
  int cnt = 0;
#pragma unroll 8
  for (int j = 0; j < 4096; ++j) cnt += (kv[j] < my) ? 1 : 0;
  const uint key = (uint)(my >> 32);
  const uint u = (key & 0x80000000u) ? (key ^ 0x80000000u) : ~key;
  vsorted[k * NN + cnt] = __uint_as_float(u);
  perm[k * NN + cnt] = (int)(my & 0xFFFFFFFFu);
}

// ---------------------------------------------------------------------------
// K4b: per-(head,chunk) sums; LDS-staged gather + shared exp precompute.
// ---------------------------------------------------------------------------
__global__ __launch_bounds__(64) void k4b_chunksum(
    const float* __restrict__ vs, const int* __restrict__ perm,
    const float* __restrict__ xt, float* __restrict__ Chi, float* __restrict__ Clo) {
  __shared__ float rows[64][64];
  __shared__ float eh[64], el[64];
  const int c = blockIdx.x, k = blockIdx.y, t = threadIdx.x;
  const int base = k * NN + c * 64;
  {
    const float v = vs[base + t];
    eh[t] = __expf(v);
    el[t] = __expf(0.2f * v);
  }
#pragma unroll
  for (int r = 0; r < 16; ++r) {
    const int i = r * 4 + (t >> 4);
    const int p = perm[base + i];
    *(float4*)&rows[i][(t & 15) * 4] =
        *(const float4*)&xt[((size_t)(k * NN + p)) * DD + (t & 15) * 4];
  }
  __syncthreads();
  float shi = 0.f, slo = 0.f, whs = 0.f, wls = 0.f;
#pragma unroll 8
  for (int i = 0; i < 64; ++i) {
    const float val = rows[i][t];
    shi += eh[i] * val; slo += el[i] * val;
    whs += eh[i]; wls += el[i];
  }
  const int cb = (k * 64 + c) * 65;
  Chi[cb + t] = shi;
  Clo[cb + t] = slo;
  if (t == 0) { Chi[cb + 64] = whs; Clo[cb + 64] = wls; }
}

// ---------------------------------------------------------------------------
// K4c: scan chunk sums (LDS-staged): CloS = excl prefix, ChiS = incl suffix
// ---------------------------------------------------------------------------
__global__ __launch_bounds__(128) void k4c_scan(
    const float* __restrict__ Chi, const float* __restrict__ Clo,
    float* __restrict__ ChiS, float* __restrict__ CloS) {
  __shared__ float schi[64 * 65];
  __shared__ float sclo[64 * 65];
  const int k = blockIdx.x, t = threadIdx.x;
  for (int idx = t; idx < 4160; idx += 128) {
    schi[idx] = Chi[k * 4160 + idx];
    sclo[idx] = Clo[k * 4160 + idx];
  }
  __syncthreads();
  if (t >= 65) return;
  float run = 0.f;
  for (int c = 0; c < 64; ++c) {
    CloS[(k * 64 + c) * 65 + t] = run;
    run += sclo[c * 65 + t];
  }
  run = 0.f;
  for (int c = 63; c >= 0; --c) {
    run += schi[c * 65 + t];
    ChiS[(k * 64 + c) * 65 + t] = run;
  }
}

// ---------------------------------------------------------------------------
// K4d: expand to per-position prefix/suffix arrays (LDS-staged).
// ---------------------------------------------------------------------------
__global__ __launch_bounds__(64) void k4d_expand(
    const float* __restrict__ vs, const int* __restrict__ perm,
    const float* __restrict__ xt, const float* __restrict__ ChiS,
    const float* __restrict__ CloS, float* __restrict__ Phi,
    float* __restrict__ Plo) {
  __shared__ float rows[64][64];
  __shared__ float eh[64], el[64];
  const int c = blockIdx.x, k = blockIdx.y, t = threadIdx.x;
  const int base = k * NN + c * 64;
  const int cb = (k * 64 + c) * 65;
  {
    const float v = vs[base + t];
    eh[t] = __expf(v);
    el[t] = __expf(0.2f * v);
  }
#pragma unroll
  for (int r = 0; r < 16; ++r) {
    const int i = r * 4 + (t >> 4);
    const int p = perm[base + i];
    *(float4*)&rows[i][(t & 15) * 4] =
        *(const float4*)&xt[((size_t)(k * NN + p)) * DD + (t & 15) * 4];
  }
  __syncthreads();
  float run = CloS[cb + t];
  float wrun = CloS[cb + 64];
  for (int i = 0; i < 64; ++i) {
    const size_t rb = ((size_t)(k * 4097) + c * 64 + i) * 65;
    Plo[rb + t] = run;
    if (t == 0) Plo[rb + 64] = wrun;
    run += el[i] * rows[i][t];
    wrun += el[i];
  }
  if (c == 63) {
    const size_t rb = ((size_t)(k * 4097) + 4096) * 65;
    Plo[rb + t] = run;
    if (t == 0) Plo[rb + 64] = wrun;
  }
  run = (c < 63) ? ChiS[cb + 65 + t] : 0.f;
  wrun = (c < 63) ? ChiS[cb + 65 + 64] : 0.f;
  for (int i = 63; i >= 0; --i) {
    run += eh[i] * rows[i][t];
    wrun += eh[i];
    const size_t rb = ((size_t)(k * 4097) + c * 64 + i) * 65;
    Phi[rb + t] = run;
    if (t == 0) Phi[rb + 64] = wrun;
  }
  if (c == 63) {
    const size_t rb = ((size_t)(k * 4097) + 4096) * 65;
    Phi[rb + t] = 0.f;
    if (t == 0) Phi[rb + 64] = 0.f;
  }
}

// ---------------------------------------------------------------------------
// K6: per query: LDS binary search + combine + tanh. 4 queries/block.
// ---------------------------------------------------------------------------
__global__ __launch_bounds__(256) void k6_final(
    const float* __restrict__ ssrc, const float* __restrict__ vsorted,
    const float* __restrict__ Phi, const float* __restrict__ Plo,
    float* __restrict__ out) {
  __shared__ float vsh[4096];
  __shared__ int posSh[4];
  const int t = threadIdx.x;
  const int q0 = blockIdx.x * 4;
  const int k = q0 >> 12;
  for (int idx = t; idx < 1024; idx += 256)
    *(float4*)&vsh[idx * 4] = *(const float4*)&vsorted[k * NN + idx * 4];
  __syncthreads();
  if (t < 4) {
    const float thr = -ssrc[q0 + t];
    int lo = 0, hi = 4096;
    while (lo < hi) {
      const int mid = (lo + hi) >> 1;
      if (vsh[mid] < thr) lo = mid + 1; else hi = mid;
    }
    posSh[t] = lo;
  }
  __syncthreads();
  const int qi = q0 + (t >> 6);
  const int d = t & 63;
  const int n = qi & 4095;
  const float u = ssrc[qi];
  const size_t rb = ((size_t)(k * 4097) + posSh[t >> 6]) * 65;
  const float eu = __expf(u), el = __expf(0.2f * u);
  const float num = eu * Phi[rb + d] + el * Plo[rb + d];
  const float den = eu * Phi[rb + 64] + el * Plo[rb + 64];
  out[(size_t)n * (KH * DD) + k * DD + d] = tanhf(num / den);
}

extern "C" void kernel_launch(void* const* d_in, const int* in_sizes, int n_in,
                              void* d_out, int out_size, void* d_ws, size_t ws_size,
                              hipStream_t stream) {
  const float* xp = (const float*)d_in[0];
  const float* xn = (const float*)d_in[1];
  const float* W = (const float*)d_in[2];
  const float* bb = (const float*)d_in[3];
  const float* Wt = (const float*)d_in[4];
  const float* av = (const float*)d_in[5];
  float* out = (float*)d_out;

  char* ws = (char*)d_ws;
  // Phi/Plo overlay the W splits (temporally disjoint: W splits consumed by
  // k1; Phi/Plo produced by k4d afterwards).
  f16* Whi    = (f16*)(ws);                       // 8 MB
  f16* Wlo    = (f16*)(ws + 8388608);             // 8 MB
  float* Phi  = (float*)(ws);                     // 8.52 MB (overlay)
  float* Plo  = (float*)(ws + 8522240);           // 8.52 MB (overlay)
  float* x    = (float*)(ws + 17044480);          // 4 MB
  float* xt   = (float*)(ws + 21238784);          // 8 MB
  f16* xh     = (f16*)(ws + 29627392);            // 2 MB
  f16* Wthi   = (f16*)(ws + 31724544);            // 256 KB
  f16* Wtlo   = (f16*)(ws + 31986688);            // 256 KB
  float* ssrc = (float*)(ws + 32248832);          // 128 KB
  float* sdst = (float*)(ws + 32379904);          // 128 KB
  float* vsort= (float*)(ws + 32510976);          // 128 KB
  int*   perm = (int*)  (ws + 32642048);          // 128 KB
  float* Chi  = (float*)(ws + 32773120);          // 133 KB
  float* Clo  = (float*)(ws + 32906240);          // 133 KB
  float* ChiS = (float*)(ws + 33039360);          // 133 KB
  float* CloS = (float*)(ws + 33172480);          // 133 KB -> ends ~33.3 MB

  k0_split<<<(HD * PP * QQ) / 1024, 256, 0, stream>>>(W, Whi, Wlo);
  k0b_wtsplit<<<(KH * DD * HD) / 1024, 256, 0, stream>>>(Wt, Wthi, Wtlo);
  k_zero4<<<(NN * HD) / 1024, 256, 0, stream>>>(x);
  k1_bilinear<<<dim3(NN / 128, 16), 256, 0, stream>>>(xp, xn, Whi, Wlo, x);
  k15_xcvt<<<(NN * HD) / 1024, 256, 0, stream>>>(x, bb, xh);
  k23_xt<<<dim3(NN / 64, 4), 256, 0, stream>>>(xh, Wthi, Wtlo, xt);
  k3_scores<<<(KH * NN) / 256, 256, 0, stream>>>(xt, av, ssrc, sdst);
  k4_rank<<<dim3(16, KH), 256, 0, stream>>>(sdst, vsort, perm);
  k4b_chunksum<<<dim3(64, KH), 64, 0, stream>>>(vsort, perm, xt, Chi, Clo);
  k4c_scan<<<KH, 128, 0, stream>>>(Chi, Clo, ChiS, CloS);
  k4d_expand<<<dim3(64, KH), 64, 0, stream>>>(vsort, perm, xt, ChiS, CloS, Phi, Plo);
  k6_final<<<(KH * NN) / 4, 256, 0, stream>>>(ssrc, vsort, Phi, Plo, out);
}

// Round 8
// 290.405 us; speedup vs baseline: 1.2919x; 1.0567x over previous
//
#include <hip/hip_runtime.h>
#include <hip/hip_bf16.h>

typedef unsigned short ushort;
typedef unsigned int uint;
typedef unsigned long long u64;
typedef _Float16 f16;

#define NN 4096
#define PP 128
#define QQ 128
#define HD 256
#define KH 8
#define DD 64
#define KK 16384  // P*Q

typedef _Float16 f16x2 __attribute__((ext_vector_type(2)));
typedef _Float16 f16x4 __attribute__((ext_vector_type(4)));
typedef _Float16 f16x8 __attribute__((ext_vector_type(8)));
typedef __fp16 fp16x2 __attribute__((ext_vector_type(2)));  // cvt_pkrtz return type
typedef float f32x4 __attribute__((ext_vector_type(4)));

__device__ inline void async_lds16(const void* g, void* l) {
  __builtin_amdgcn_global_load_lds(
      (const __attribute__((address_space(1))) unsigned int*)g,
      (__attribute__((address_space(3))) unsigned int*)l, 16, 0, 0);
}

// ---------------------------------------------------------------------------
// K0: split W and Wt fp32 -> f16 hi + f16 lo (exact residual) in one launch.
// ---------------------------------------------------------------------------
__global__ __launch_bounds__(256) void k0_split2(
    const float* __restrict__ W, const float* __restrict__ Wt,
    f16* __restrict__ hiW, f16* __restrict__ loW,
    f16* __restrict__ hiT, f16* __restrict__ loT) {
  const int i = (blockIdx.x * 256 + threadIdx.x) * 4;
  const float* src;
  f16 *hi, *lo;
  int off;
  if (i < HD * PP * QQ) { src = W; hi = hiW; lo = loW; off = i; }
  else { src = Wt; hi = hiT; lo = loT; off = i - HD * PP * QQ; }
  const float4 w = *(const float4*)&src[off];
  const float wf[4] = {w.x, w.y, w.z, w.w};
  f16x4 hv, lv;
#pragma unroll
  for (int j = 0; j < 4; ++j) {
    const f16 h = (f16)wf[j];
    hv[j] = h;
    lv[j] = (f16)(wf[j] - (float)h);
  }
  *(f16x4*)&hi[off] = hv;
  *(f16x4*)&lo[off] = lv;
}

__global__ __launch_bounds__(256) void k_zero4(float* __restrict__ p) {
  const int i = (blockIdx.x * 256 + threadIdx.x) * 4;
  *(float4*)&p[i] = make_float4(0.f, 0.f, 0.f, 0.f);
}

// ---------------------------------------------------------------------------
// K1: bilinear via 2-pass fp16 MFMA. C[4096,256] = Z @ (Whi+Wlo)^T, Z rounded
// to fp16 on the fly. Block 128n x 256h, BK=32, K-split 16 -> atomicAdd.
// MFMA issue order: Bh pass then Bl pass per j (acc reuse distance 4, hides
// MFMA latency — distance-1 pairs stalled the wave).
// ---------------------------------------------------------------------------
__global__ __launch_bounds__(256, 2) void k1_bilinear(
    const float* __restrict__ xp, const float* __restrict__ xn,
    const f16* __restrict__ Whi, const f16* __restrict__ Wlo,
    float* __restrict__ xout) {
  __shared__ f16 whi[256 * 32];   // [h][k], XOR-swizzled 16B segs
  __shared__ f16 wlo[256 * 32];
  __shared__ f16 zhi[128 * 40];   // [n][k] padded 32->40
  __shared__ float xpt[8][128];   // [p][n]

  const int t = threadIdx.x;
  const int n0 = blockIdx.x * 128;
  const int kb = blockIdx.y * (KK / 16);  // 1024-wide K chunk
  const int pb = kb >> 7;                 // 8 p values per block

  for (int idx = t; idx < 1024; idx += 256) {
    const int p = idx & 7, n = idx >> 3;
    xpt[p][n] = xp[(size_t)(n0 + n) * PP + pb + p];
  }

  const int l = t & 63, w = t >> 6;
  const int wr = (w >> 1) * 64, wc = (w & 1) * 128;

  int aoff[4], boff[8];
#pragma unroll
  for (int i = 0; i < 4; ++i)
    aoff[i] = (wr + i * 16 + (l & 15)) * 40 + (l >> 4) * 8;
#pragma unroll
  for (int j = 0; j < 8; ++j) {
    const int hr = wc + j * 16 + (l & 15);
    boff[j] = hr * 32 + (((l >> 4) ^ ((hr ^ (hr >> 2)) & 3)) * 8);
  }

  const int shb = t >> 2, seg = t & 3;
  int gsw[4];
#pragma unroll
  for (int g = 0; g < 4; ++g) {
    const int r = shb + 64 * g;
    gsw[g] = seg ^ ((r ^ (r >> 2)) & 3);
  }

  const int zn = t >> 1, zko = (t & 1) * 16;

  f32x4 acc[4][8];
#pragma unroll
  for (int i = 0; i < 4; ++i)
#pragma unroll
    for (int j = 0; j < 8; ++j) acc[i][j] = (f32x4)0.f;

  for (int c = 0; c < 32; ++c) {
    const int kc = kb + c * 32;
    const int pl = c >> 2;             // local p index (0..7)
    const int q0 = (c & 3) * 32;       // q base within row

    __syncthreads();  // previous step's fragment reads done

#pragma unroll
    for (int g = 0; g < 4; ++g) {
      const int r = shb + 64 * g;
      async_lds16(Whi + (size_t)r * KK + kc + gsw[g] * 8, whi + r * 32 + seg * 8);
      async_lds16(Wlo + (size_t)r * KK + kc + gsw[g] * 8, wlo + r * 32 + seg * 8);
    }

    // form Z tile: 16 elems/thread, fp16 round via pkrtz (2 elems/op)
    {
      const float xpv = xpt[pl][zn];
      const float* xr = xn + (size_t)(n0 + zn) * QQ + q0 + zko;
      float4 v0 = ((const float4*)xr)[0];
      float4 v1 = ((const float4*)xr)[1];
      float4 v2 = ((const float4*)xr)[2];
      float4 v3 = ((const float4*)xr)[3];
      float zz[16] = {v0.x, v0.y, v0.z, v0.w, v1.x, v1.y, v1.z, v1.w,
                      v2.x, v2.y, v2.z, v2.w, v3.x, v3.y, v3.z, v3.w};
      union { uint u[8]; uint4 q[2]; } ph;
#pragma unroll
      for (int j = 0; j < 8; ++j) {
        union { fp16x2 h; uint u; } cv;
        cv.h = __builtin_amdgcn_cvt_pkrtz(xpv * zz[2 * j], xpv * zz[2 * j + 1]);
        ph.u[j] = cv.u;
      }
      const int zo = zn * 40 + zko;
      *(uint4*)&zhi[zo] = ph.q[0];
      *(uint4*)&zhi[zo + 8] = ph.q[1];
    }

    __syncthreads();  // W (vmcnt drained) + Z visible

    f16x8 Ah[4];
#pragma unroll
    for (int i = 0; i < 4; ++i) Ah[i] = *(const f16x8*)&zhi[aoff[i]];
#pragma unroll
    for (int j = 0; j < 8; ++j) {
      const f16x8 Bh = *(const f16x8*)&whi[boff[j]];
      const f16x8 Bl = *(const f16x8*)&wlo[boff[j]];
#pragma unroll
      for (int i = 0; i < 4; ++i)
        acc[i][j] = __builtin_amdgcn_mfma_f32_16x16x32_f16(Ah[i], Bh, acc[i][j], 0, 0, 0);
#pragma unroll
      for (int i = 0; i < 4; ++i)
        acc[i][j] = __builtin_amdgcn_mfma_f32_16x16x32_f16(Ah[i], Bl, acc[i][j], 0, 0, 0);
    }
  }

#pragma unroll
  for (int i = 0; i < 4; ++i)
#pragma unroll
    for (int j = 0; j < 8; ++j) {
      const int row = n0 + wr + i * 16 + (l >> 4) * 4;
      const int col = wc + j * 16 + (l & 15);
#pragma unroll
      for (int r = 0; r < 4; ++r)
        atomicAdd(&xout[(size_t)(row + r) * HD + col], acc[i][j][r]);
    }
}

// ---------------------------------------------------------------------------
// K23: xt[k][n][d] = sum_h (x[n][h]+b[h]) * (Wthi+Wtlo)[k*64+d][h]
// 2-pass fp16 MFMA; bias-add + f16 convert fused into the A-stage.
// Block 64n x 128cols, K=256 in BK=32 chunks. grid (64, 4).
// ---------------------------------------------------------------------------
__global__ __launch_bounds__(256) void k23_xt(
    const float* __restrict__ x, const float* __restrict__ bb,
    const f16* __restrict__ Wthi, const f16* __restrict__ Wtlo,
    float* __restrict__ xt) {
  __shared__ f16 ah[64 * 40];
  __shared__ f16 bh[128 * 32];
  __shared__ f16 bl[128 * 32];
  const int t = threadIdx.x;
  const int n0 = blockIdx.x * 64;
  const int c0 = blockIdx.y * 128;
  const int l = t & 63, w = t >> 6;
  const int wn = (w & 1) * 32, wcc = (w >> 1) * 64;

  int aoff[2], boff[4];
#pragma unroll
  for (int i = 0; i < 2; ++i)
    aoff[i] = (wn + i * 16 + (l & 15)) * 40 + (l >> 4) * 8;
#pragma unroll
  for (int j = 0; j < 4; ++j) {
    const int hr = wcc + j * 16 + (l & 15);
    boff[j] = hr * 32 + (((l >> 4) ^ ((hr ^ (hr >> 2)) & 3)) * 8);
  }

  f32x4 acc[2][4];
#pragma unroll
  for (int i = 0; i < 2; ++i)
#pragma unroll
    for (int j = 0; j < 4; ++j) acc[i][j] = (f32x4)0.f;

  for (int kc = 0; kc < HD; kc += 32) {
    __syncthreads();
    {  // A stage: read x fp32 + bias, cvt f16, store 16B
      const int row = t >> 2, sg = t & 3;
      const float* xr = &x[(size_t)(n0 + row) * HD + kc + sg * 8];
      const float4 xa = ((const float4*)xr)[0];
      const float4 xb = ((const float4*)xr)[1];
      const float4 ba = *(const float4*)&bb[kc + sg * 8];
      const float4 bv = *(const float4*)&bb[kc + sg * 8 + 4];
      f16x8 o;
      o[0] = (f16)(xa.x + ba.x); o[1] = (f16)(xa.y + ba.y);
      o[2] = (f16)(xa.z + ba.z); o[3] = (f16)(xa.w + ba.w);
      o[4] = (f16)(xb.x + bv.x); o[5] = (f16)(xb.y + bv.y);
      o[6] = (f16)(xb.z + bv.z); o[7] = (f16)(xb.w + bv.w);
      *(f16x8*)&ah[row * 40 + sg * 8] = o;
    }
#pragma unroll
    for (int g = 0; g < 2; ++g) {  // B stage: 128 cols x 4 segs = 512 slots
      const int slot = g * 256 + t;
      const int col = slot >> 2, ps = slot & 3;
      const int ls = ps ^ ((col ^ (col >> 2)) & 3);
      *(uint4*)&bh[col * 32 + ps * 8] =
          *(const uint4*)&Wthi[(size_t)(c0 + col) * HD + kc + ls * 8];
      *(uint4*)&bl[col * 32 + ps * 8] =
          *(const uint4*)&Wtlo[(size_t)(c0 + col) * HD + kc + ls * 8];
    }
    __syncthreads();
    f16x8 Af[2];
#pragma unroll
    for (int i = 0; i < 2; ++i) Af[i] = *(const f16x8*)&ah[aoff[i]];
#pragma unroll
    for (int j = 0; j < 4; ++j) {
      const f16x8 Bh = *(const f16x8*)&bh[boff[j]];
      const f16x8 Bl = *(const f16x8*)&bl[boff[j]];
#pragma unroll
      for (int i = 0; i < 2; ++i)
        acc[i][j] = __builtin_amdgcn_mfma_f32_16x16x32_f16(Af[i], Bh, acc[i][j], 0, 0, 0);
#pragma unroll
      for (int i = 0; i < 2; ++i)
        acc[i][j] = __builtin_amdgcn_mfma_f32_16x16x32_f16(Af[i], Bl, acc[i][j], 0, 0, 0);
    }
  }
#pragma unroll
  for (int i = 0; i < 2; ++i)
#pragma unroll
    for (int j = 0; j < 4; ++j) {
      const int row = n0 + wn + i * 16 + (l >> 4) * 4;
      const int colg = c0 + wcc + j * 16 + (l & 15);
      const int k = colg >> 6, d = colg & 63;
#pragma unroll
      for (int r = 0; r < 4; ++r)
        xt[((size_t)(k * NN + row + r)) * DD + d] = acc[i][j][r];
    }
}

// ---------------------------------------------------------------------------
// K3: u = xt·a_src, v = xt·a_dst
// ---------------------------------------------------------------------------
__global__ __launch_bounds__(256) void k3_scores(
    const float* __restrict__ xt, const float* __restrict__ av,
    float* __restrict__ ssrc, float* __restrict__ sdst) {
  const int tid = blockIdx.x * 256 + threadIdx.x;
  const int k = tid >> 12;
  const float* xr = xt + (long)tid * DD;
  const float* a = av + k * (2 * DD);
  float s1 = 0.f, s2 = 0.f;
#pragma unroll
  for (int d = 0; d < DD; d += 4) {
    const float4 xv = *(const float4*)&xr[d];
    const float4 a1 = *(const float4*)&a[d];
    const float4 a2 = *(const float4*)&a[DD + d];
    s1 += xv.x * a1.x + xv.y * a1.y + xv.z * a1.z + xv.w * a1.w;
    s2 += xv.x * a2.x + xv.y * a2.y + xv.z * a2.z + xv.w * a2.w;
  }
  ssrc[tid] = s1;
  sdst[tid] = s2;
}

// ---------------------------------------------------------------------------
// K4a: rank-and-scatter "sort" (exact total order via packed u64 keys)
// ---------------------------------------------------------------------------
__global__ __launch_bounds__(256) void k4_rank(
    const float* __restrict__ sdst, float* __restrict__ vsorted,
    int* __restrict__ perm) {
  __shared__ u64 kv[4096];
  const int k = blockIdx.y, t = threadIdx.x;
  for (int i = t; i < 4096; i += 256) {
    const uint u = __float_as_uint(sdst[k * NN + i]);
    const uint key = (u & 0x80000000u) ? ~u : (u | 0x80000000u);
    kv[i] = ((u64)key << 32) | (uint)i;
  }
  __syncthreads();
  const int m = blockIdx.x * 256 + t;
  const u64 my = kv[m];
  int cnt = 0;
#pragma unroll 16
  for (int j = 0; j < 4096; ++j) cnt += (kv[j] < my) ? 1 : 0;
  const uint key = (uint)(my >> 32);
  const uint u = (key & 0x80000000u) ? (key ^ 0x80000000u) : ~key;
  vsorted[k * NN + cnt] = __uint_as_float(u);
  perm[k * NN + cnt] = (int)(my & 0xFFFFFFFFu);
}

// ---------------------------------------------------------------------------
// K4b: per-(head,chunk) sums; LDS-staged gather + shared exp precompute.
// ---------------------------------------------------------------------------
__global__ __launch_bounds__(64) void k4b_chunksum(
    const float* __restrict__ vs, const int* __restrict__ perm,
    const float* __restrict__ xt, float* __restrict__ Chi, float* __restrict__ Clo) {
  __shared__ float rows[64][64];
  __shared__ float eh[64], el[64];
  const int c = blockIdx.x, k = blockIdx.y, t = threadIdx.x;
  const int base = k * NN + c * 64;
  {
    const float v = vs[base + t];
    eh[t] = __expf(v);
    el[t] = __expf(0.2f * v);
  }
#pragma unroll
  for (int r = 0; r < 16; ++r) {
    const int i = r * 4 + (t >> 4);
    const int p = perm[base + i];
    *(float4*)&rows[i][(t & 15) * 4] =
        *(const float4*)&xt[((size_t)(k * NN + p)) * DD + (t & 15) * 4];
  }
  __syncthreads();
  float shi = 0.f, slo = 0.f, whs = 0.f, wls = 0.f;
#pragma unroll 8
  for (int i = 0; i < 64; ++i) {
    const float val = rows[i][t];
    shi += eh[i] * val; slo += el[i] * val;
    whs += eh[i]; wls += el[i];
  }
  const int cb = (k * 64 + c) * 65;
  Chi[cb + t] = shi;
  Clo[cb + t] = slo;
  if (t == 0) { Chi[cb + 64] = whs; Clo[cb + 64] = wls; }
}

// ---------------------------------------------------------------------------
// K4c: scan chunk sums (LDS-staged): CloS = excl prefix, ChiS = incl suffix
// ---------------------------------------------------------------------------
__global__ __launch_bounds__(128) void k4c_scan(
    const float* __restrict__ Chi, const float* __restrict__ Clo,
    float* __restrict__ ChiS, float* __restrict__ CloS) {
  __shared__ float schi[64 * 65];
  __shared__ float sclo[64 * 65];
  const int k = blockIdx.x, t = threadIdx.x;
  for (int idx = t; idx < 4160; idx += 128) {
    schi[idx] = Chi[k * 4160 + idx];
    sclo[idx] = Clo[k * 4160 + idx];
  }
  __syncthreads();
  if (t >= 65) return;
  float run = 0.f;
  for (int c = 0; c < 64; ++c) {
    CloS[(k * 64 + c) * 65 + t] = run;
    run += sclo[c * 65 + t];
  }
  run = 0.f;
  for (int c = 63; c >= 0; --c) {
    run += schi[c * 65 + t];
    ChiS[(k * 64 + c) * 65 + t] = run;
  }
}

// ---------------------------------------------------------------------------
// K4d: expand to per-position prefix/suffix arrays (LDS-staged).
// ---------------------------------------------------------------------------
__global__ __launch_bounds__(64) void k4d_expand(
    const float* __restrict__ vs, const int* __restrict__ perm,
    const float* __restrict__ xt, const float* __restrict__ ChiS,
    const float* __restrict__ CloS, float* __restrict__ Phi,
    float* __restrict__ Plo) {
  __shared__ float rows[64][64];
  __shared__ float eh[64], el[64];
  const int c = blockIdx.x, k = blockIdx.y, t = threadIdx.x;
  const int base = k * NN + c * 64;
  const int cb = (k * 64 + c) * 65;
  {
    const float v = vs[base + t];
    eh[t] = __expf(v);
    el[t] = __expf(0.2f * v);
  }
#pragma unroll
  for (int r = 0; r < 16; ++r) {
    const int i = r * 4 + (t >> 4);
    const int p = perm[base + i];
    *(float4*)&rows[i][(t & 15) * 4] =
        *(const float4*)&xt[((size_t)(k * NN + p)) * DD + (t & 15) * 4];
  }
  __syncthreads();
  float run = CloS[cb + t];
  float wrun = CloS[cb + 64];
  for (int i = 0; i < 64; ++i) {
    const size_t rb = ((size_t)(k * 4097) + c * 64 + i) * 65;
    Plo[rb + t] = run;
    if (t == 0) Plo[rb + 64] = wrun;
    run += el[i] * rows[i][t];
    wrun += el[i];
  }
  if (c == 63) {
    const size_t rb = ((size_t)(k * 4097) + 4096) * 65;
    Plo[rb + t] = run;
    if (t == 0) Plo[rb + 64] = wrun;
  }
  run = (c < 63) ? ChiS[cb + 65 + t] : 0.f;
  wrun = (c < 63) ? ChiS[cb + 65 + 64] : 0.f;
  for (int i = 63; i >= 0; --i) {
    run += eh[i] * rows[i][t];
    wrun += eh[i];
    const size_t rb = ((size_t)(k * 4097) + c * 64 + i) * 65;
    Phi[rb + t] = run;
    if (t == 0) Phi[rb + 64] = wrun;
  }
  if (c == 63) {
    const size_t rb = ((size_t)(k * 4097) + 4096) * 65;
    Phi[rb + t] = 0.f;
    if (t == 0) Phi[rb + 64] = 0.f;
  }
}

// ---------------------------------------------------------------------------
// K6: per query: LDS binary search + combine + tanh. 4 queries/block.
// ---------------------------------------------------------------------------
__global__ __launch_bounds__(256) void k6_final(
    const float* __restrict__ ssrc, const float* __restrict__ vsorted,
    const float* __restrict__ Phi, const float* __restrict__ Plo,
    float* __restrict__ out) {
  __shared__ float vsh[4096];
  __shared__ int posSh[4];
  const int t = threadIdx.x;
  const int q0 = blockIdx.x * 4;
  const int k = q0 >> 12;
  for (int idx = t; idx < 1024; idx += 256)
    *(float4*)&vsh[idx * 4] = *(const float4*)&vsorted[k * NN + idx * 4];
  __syncthreads();
  if (t < 4) {
    const float thr = -ssrc[q0 + t];
    int lo = 0, hi = 4096;
    while (lo < hi) {
      const int mid = (lo + hi) >> 1;
      if (vsh[mid] < thr) lo = mid + 1; else hi = mid;
    }
    posSh[t] = lo;
  }
  __syncthreads();
  const int qi = q0 + (t >> 6);
  const int d = t & 63;
  const int n = qi & 4095;
  const float u = ssrc[qi];
  const size_t rb = ((size_t)(k * 4097) + posSh[t >> 6]) * 65;
  const float eu = __expf(u), el = __expf(0.2f * u);
  const float num = eu * Phi[rb + d] + el * Plo[rb + d];
  const float den = eu * Phi[rb + 64] + el * Plo[rb + 64];
  out[(size_t)n * (KH * DD) + k * DD + d] = tanhf(num / den);
}

extern "C" void kernel_launch(void* const* d_in, const int* in_sizes, int n_in,
                              void* d_out, int out_size, void* d_ws, size_t ws_size,
                              hipStream_t stream) {
  const float* xp = (const float*)d_in[0];
  const float* xn = (const float*)d_in[1];
  const float* W = (const float*)d_in[2];
  const float* bb = (const float*)d_in[3];
  const float* Wt = (const float*)d_in[4];
  const float* av = (const float*)d_in[5];
  float* out = (float*)d_out;

  char* ws = (char*)d_ws;
  // Phi/Plo overlay the W splits (temporally disjoint: W splits consumed by
  // k1/k23; Phi/Plo produced by k4d afterwards).
  f16* Whi    = (f16*)(ws);                       // 8 MB
  f16* Wlo    = (f16*)(ws + 8388608);             // 8 MB
  float* Phi  = (float*)(ws);                     // 8.52 MB (overlay)
  float* Plo  = (float*)(ws + 8522240);           // 8.52 MB (overlay)
  float* x    = (float*)(ws + 17044480);          // 4 MB
  float* xt   = (float*)(ws + 21238784);          // 8 MB
  f16* Wthi   = (f16*)(ws + 31724544);            // 256 KB
  f16* Wtlo   = (f16*)(ws + 31986688);            // 256 KB
  float* ssrc = (float*)(ws + 32248832);          // 128 KB
  float* sdst = (float*)(ws + 32379904);          // 128 KB
  float* vsort= (float*)(ws + 32510976);          // 128 KB
  int*   perm = (int*)  (ws + 32642048);          // 128 KB
  float* Chi  = (float*)(ws + 32773120);          // 133 KB
  float* Clo  = (float*)(ws + 32906240);          // 133 KB
  float* ChiS = (float*)(ws + 33039360);          // 133 KB
  float* CloS = (float*)(ws + 33172480);          // 133 KB -> ends ~33.3 MB

  k0_split2<<<(HD * PP * QQ + KH * DD * HD) / 1024, 256, 0, stream>>>(
      W, Wt, Whi, Wlo, Wthi, Wtlo);
  k_zero4<<<(NN * HD) / 1024, 256, 0, stream>>>(x);
  k1_bilinear<<<dim3(NN / 128, 16), 256, 0, stream>>>(xp, xn, Whi, Wlo, x);
  k23_xt<<<dim3(NN / 64, 4), 256, 0, stream>>>(x, bb, Wthi, Wtlo, xt);
  k3_scores<<<(KH * NN) / 256, 256, 0, stream>>>(xt, av, ssrc, sdst);
  k4_rank<<<dim3(16, KH), 256, 0, stream>>>(sdst, vsort, perm);
  k4b_chunksum<<<dim3(64, KH), 64, 0, stream>>>(vsort, perm, xt, Chi, Clo);
  k4c_scan<<<KH, 128, 0, stream>>>(Chi, Clo, ChiS, CloS);
  k4d_expand<<<dim3(64, KH), 64, 0, stream>>>(vsort, perm, xt, ChiS, CloS, Phi, Plo);
  k6_final<<<(KH * NN) / 4, 256, 0, stream>>>(ssrc, vsort, Phi, Plo, out);
}